// Round 1
// baseline (580.784 us; speedup 1.0000x reference)
//
#include <hip/hip_runtime.h>

// Soft-DTW (gamma=1), batched 64 x (1024 vs 1024, 2-D points), anti-diagonal
// wavefront. One block per batch element, thread t = DP row t.
//
// Recurrence (diagonal d, row i, col j = d-i):
//   R_d[i] = D[i,j] + softmin( R_{d-2}[i-1],   // diagonal
//                              R_{d-1}[i-1],   // up    (reference "right")
//                              R_{d-1}[i]   )  // left  (reference "down")
//   softmin(a,b,c) = m - ln(e^{m-a}+e^{m-b}+e^{m-c}),  m = min(a,b,c)
//
// State per thread: my_prev = R_{d-1}[t] (register),
//                   nb_prev = R_{d-1}[t-1], nb_prev2 = R_{d-2}[t-1]
// Neighbor values flow through a double-buffered LDS line; one
// __syncthreads per diagonal (write buf[d&1] -> barrier -> read buf[d&1];
// buf[d&1] is next written at step d+2, which is after barrier d+1, and
// every reader passed barrier d+1 only after its step-d read -> race-free).

#define N 1024
#define NDIAG (2 * N - 1) // 2047

__device__ __forceinline__ float sqdist2(float2 a, float2 b) {
    float dx = a.x - b.x;
    float dy = a.y - b.y;
    return dx * dx + dy * dy;
}

__global__ __launch_bounds__(1024) void dtw_kernel(
    const float2* __restrict__ snake,
    const float2* __restrict__ contour,
    float* __restrict__ out)
{
    const int b = blockIdx.x;
    const int t = threadIdx.x;
    const float INF = __builtin_inff();

    __shared__ float2 c[N];        // contour points for this batch
    __shared__ float S0[N + 1];    // R line, even diagonals (index +1 shift)
    __shared__ float S1[N + 1];    // R line, odd diagonals
    __shared__ float initvals[3];  // R0[0], R1[0], R1[1]

    const float2* sg = snake + (size_t)b * N;
    const float2* cg = contour + (size_t)b * N;

    const float2 sp = sg[t];       // snake point: loop-invariant per thread
    c[t] = cg[t];
    S0[t + 1] = INF;
    S1[t + 1] = INF;
    if (t == 0) {
        S0[0] = INF;
        S1[0] = INF;
        // Diagonals 0 and 1 (reference `init`):
        //   R0[0] = D(0,0);  R1[0] = D(0,1)+D(0,0);  R1[1] = D(1,0)+D(0,0)
        float2 s0 = sg[0], s1 = sg[1];
        float2 c0 = cg[0], c1 = cg[1];
        float d00 = sqdist2(s0, c0);
        initvals[0] = d00;
        initvals[1] = sqdist2(s0, c1) + d00;
        initvals[2] = sqdist2(s1, c0) + d00;
    }
    __syncthreads();

    // Register state entering the loop at d = 2 (i.e. holding diag 1 / 0):
    float my_prev  = INF;  // R_{d-1}[t]
    float nb_prev  = INF;  // R_{d-1}[t-1]
    float nb_prev2 = INF;  // R_{d-2}[t-1]
    if (t == 0) {
        my_prev = initvals[1];
    } else if (t == 1) {
        my_prev  = initvals[2];
        nb_prev  = initvals[1];
        nb_prev2 = initvals[0];
    } else if (t == 2) {
        nb_prev = initvals[2];
    }

    for (int d = 2; d < NDIAG; ++d) {
        float* Sw = (d & 1) ? S1 : S0;
        const bool active = (d >= t) && (d - t < N);
        if (active) {
            float2 cp = c[d - t];
            float dx = sp.x - cp.x;
            float dy = sp.y - cp.y;
            float cost = dx * dx + dy * dy;
            float m = fminf(fminf(my_prev, nb_prev), nb_prev2);
            // m is finite for every active cell (>=1 finite predecessor);
            // __expf(-inf) = 0 handles the boundary cases exactly.
            float s = __expf(m - my_prev) + __expf(m - nb_prev)
                    + __expf(m - nb_prev2);
            float r = cost + m - __logf(s);
            Sw[t + 1] = r;
            my_prev = r;
        }
        __syncthreads();
        nb_prev2 = nb_prev;
        nb_prev  = Sw[t];
    }

    // Thread N-1's my_prev now holds R[N-1, N-1] (written at d = 2046).
    if (t == N - 1) {
        atomicAdd(out, my_prev * (1.0f / 64.0f));
    }
}

extern "C" void kernel_launch(void* const* d_in, const int* in_sizes, int n_in,
                              void* d_out, int out_size, void* d_ws, size_t ws_size,
                              hipStream_t stream) {
    const float2* snake   = (const float2*)d_in[0];
    const float2* contour = (const float2*)d_in[1];
    float* out = (float*)d_out;
    // Harness re-poisons d_out to 0xAA before every timed launch.
    hipMemsetAsync(out, 0, sizeof(float), stream);
    dtw_kernel<<<64, 1024, 0, stream>>>(snake, contour, out);
}